// Round 10
// baseline (114.181 us; speedup 1.0000x reference)
//
#include <hip/hip_runtime.h>
#include <math.h>

#define DD 4096
#define EE 64
#define NTOK 8192
#define BM 32            // tokens per block (fused: full K per block)
#define KC 64            // K-chunk staged in LDS
#define XSTR 72          // LDS row stride in bf16 (144 B: 16B-aligned, ~2-way)
#define NCH (DD / KC)    // 64 chunks
#define TAU 4e-3f        // flag threshold; 4-term split err ~1.5e-4 typ max

typedef __attribute__((ext_vector_type(8))) short short8;
typedef __attribute__((ext_vector_type(4))) float f32x4;

__device__ __forceinline__ unsigned short f2bf(float f) {   // RNE bf16
    unsigned int u = __float_as_uint(f);
    return (unsigned short)((u + 0x7FFFu + ((u >> 16) & 1u)) >> 16);
}
__device__ __forceinline__ float bf2f(unsigned short h) {
    return __uint_as_float((unsigned int)h << 16);
}

// ---------------------------------------------------------------------------
// prep: W -> bf16 hi/lo split (Wh, Wl); zero the flag counter.
// ---------------------------------------------------------------------------
__global__ void moirai_prep(const float* __restrict__ W,
                            unsigned short* __restrict__ Wh,
                            unsigned short* __restrict__ Wl,
                            int* __restrict__ count) {
    int i = blockIdx.x * 256 + threadIdx.x;
    if (i == 0) *count = 0;
    if (i < EE * DD) {
        float w = W[i];
        unsigned short h = f2bf(w);
        Wh[i] = h;
        Wl[i] = f2bf(w - bf2f(h));
    }
}

// ---------------------------------------------------------------------------
// fused gemm+topk: grid=256 (1/CU), 512 thr (8 waves). Block owns 32 tokens,
// full K. Wave (mt=wv&1, nt=wv>>1) owns one 16x16 output tile with FOUR
// independent accs (hh,hl,lh,ll) -> 4-term split-bf16, no dependent chains.
// 2-deep register prefetch feeds single-buffer LDS (2 barriers/chunk).
// Epilogue: logits -> LDS, per-wave validated top-2 butterfly + flag.
// ---------------------------------------------------------------------------
__global__ __launch_bounds__(512, 2) void moirai_gemm(
        const float* __restrict__ x,
        const unsigned short* __restrict__ Wh,
        const unsigned short* __restrict__ Wl,
        const float* __restrict__ bias,
        float* __restrict__ out,
        int* __restrict__ count, int* __restrict__ list) {
    __shared__ __align__(16) unsigned short xs_h[BM * XSTR];  // 4.6 KB
    __shared__ __align__(16) unsigned short xs_l[BM * XSTR];  // 4.6 KB
    __shared__ __align__(16) unsigned short ws_h[EE * XSTR];  // 9.2 KB
    __shared__ __align__(16) unsigned short ws_l[EE * XSTR];  // 9.2 KB
    __shared__ float lg[BM][EE + 1];                          // 8.3 KB

    const int t    = threadIdx.x;
    const int lane = t & 63;
    const int wv   = t >> 6;          // 0..7
    const int mt   = wv & 1;          // m-tile (16 tok)
    const int nt   = wv >> 1;         // n-tile (16 exp)
    const int m0   = blockIdx.x * BM;

    const int fr = lane & 15;         // A/B fragment row
    const int fg = lane >> 4;         // k-group

    const int xrow = t >> 4, xseg = t & 15;   // x stage: 32 rows x 16 f32x4
    const int wrow = t >> 3, wseg = t & 7;    // W stage: 64 rows x 8 uint4

    f32x4 aHH = {0.f,0.f,0.f,0.f}, aHL = {0.f,0.f,0.f,0.f};
    f32x4 aLH = {0.f,0.f,0.f,0.f}, aLL = {0.f,0.f,0.f,0.f};

    float4 xA, xB; uint4 whA, wlA, whB, wlB;

    auto ldx = [&](int c, float4& xr, uint4& wh, uint4& wl) {
        xr = *(const float4*)(x + (size_t)(m0 + xrow) * DD + c * KC + xseg * 4);
        wh = *(const uint4*)(Wh + (size_t)wrow * DD + c * KC + wseg * 8);
        wl = *(const uint4*)(Wl + (size_t)wrow * DD + c * KC + wseg * 8);
    };
    auto stg = [&](const float4& xr, const uint4& wh, const uint4& wl) {
        unsigned short h0 = f2bf(xr.x), h1 = f2bf(xr.y);
        unsigned short h2 = f2bf(xr.z), h3 = f2bf(xr.w);
        unsigned short l0 = f2bf(xr.x - bf2f(h0)), l1 = f2bf(xr.y - bf2f(h1));
        unsigned short l2 = f2bf(xr.z - bf2f(h2)), l3 = f2bf(xr.w - bf2f(h3));
        uint2 ph = {(unsigned int)h0 | ((unsigned int)h1 << 16),
                    (unsigned int)h2 | ((unsigned int)h3 << 16)};
        uint2 pl = {(unsigned int)l0 | ((unsigned int)l1 << 16),
                    (unsigned int)l2 | ((unsigned int)l3 << 16)};
        *(uint2*)&xs_h[xrow * XSTR + xseg * 4] = ph;
        *(uint2*)&xs_l[xrow * XSTR + xseg * 4] = pl;
        *(uint4*)&ws_h[wrow * XSTR + wseg * 8] = wh;
        *(uint4*)&ws_l[wrow * XSTR + wseg * 8] = wl;
    };

    // prologue: stage chunk 0, have chunk 1 in flight
    ldx(0, xA, whA, wlA);
    stg(xA, whA, wlA);
    ldx(1, xB, whB, wlB);
    __syncthreads();

    for (int c = 0; c < NCH; c++) {
        const bool even = ((c & 1) == 0);
        if (c + 2 < NCH) {            // 2-deep prefetch into the freed set
            if (even) ldx(c + 2, xA, whA, wlA);
            else      ldx(c + 2, xB, whB, wlB);
        }

#pragma unroll
        for (int h = 0; h < 2; h++) { // two K=32 MFMA halves per chunk
            const int ao = (mt * 16 + fr) * XSTR + h * 32 + fg * 8;
            const int bo = (nt * 16 + fr) * XSTR + h * 32 + fg * 8;
            short8 ah = *(const short8*)&xs_h[ao];
            short8 al = *(const short8*)&xs_l[ao];
            short8 bh = *(const short8*)&ws_h[bo];
            short8 bl = *(const short8*)&ws_l[bo];
            aHH = __builtin_amdgcn_mfma_f32_16x16x32_bf16(ah, bh, aHH, 0, 0, 0);
            aHL = __builtin_amdgcn_mfma_f32_16x16x32_bf16(ah, bl, aHL, 0, 0, 0);
            aLH = __builtin_amdgcn_mfma_f32_16x16x32_bf16(al, bh, aLH, 0, 0, 0);
            aLL = __builtin_amdgcn_mfma_f32_16x16x32_bf16(al, bl, aLL, 0, 0, 0);
        }

        __syncthreads();              // reads of chunk c done
        if (c + 1 < NCH) {
            if (even) stg(xB, whB, wlB);   // set holding chunk c+1
            else      stg(xA, whA, wlA);
            __syncthreads();          // staging visible
        }
    }

    // C/D layout (verified m89/m91): col = lane&15 (expert), row = fg*4+j (tok)
#pragma unroll
    for (int j = 0; j < 4; j++) {
        float v = (aHH[j] + aHL[j]) + (aLH[j] + aLL[j]);   // fixed order
        lg[mt * 16 + fg * 4 + j][nt * 16 + fr] = v;
    }
    __syncthreads();

    // per-wave topk: wave wv handles tokens wv*4..wv*4+3 (validated butterfly)
    const float blv = bias[lane];
#pragma unroll
    for (int tt = 0; tt < 4; tt++) {
        const int tok = wv * 4 + tt;
        float v = lg[tok][lane] + blv;

        float v1 = v, v2 = -3.4e38f;
        int   i1 = lane, i2 = 127;
#pragma unroll
        for (int off = 1; off < 64; off <<= 1) {
            float u1 = __shfl_xor(v1, off);
            float u2 = __shfl_xor(v2, off);
            int   j1 = __shfl_xor(i1, off);
            int   j2 = __shfl_xor(i2, off);
            bool u1_beats_v1 = (u1 > v1) || (u1 == v1 && j1 < i1);
            if (u1_beats_v1) {
                bool v1_beats_u2 = (v1 > u2) || (v1 == u2 && i1 < j2);
                if (v1_beats_u2) { v2 = v1; i2 = i1; }
                else             { v2 = u2; i2 = j2; }
                v1 = u1; i1 = j1;
            } else {
                bool u1_beats_v2 = (u1 > v2) || (u1 == v2 && j1 < i2);
                if (u1_beats_v2) { v2 = u1; i2 = j1; }
            }
        }

        float ve = (lane == i1 || lane == i2) ? -3.4e38f : v;
#pragma unroll
        for (int off = 1; off < 64; off <<= 1)
            ve = fmaxf(ve, __shfl_xor(ve, off));

        if (lane == 0) {
            const int token = m0 + tok;
            if ((v1 - v2 < TAU) || (v2 - ve < TAU)) {
                int pos = atomicAdd(count, 1);
                list[pos] = token;
            }
            double ex = exp((double)v2 - (double)v1);   // v1 >= v2 -> stable
            double s  = 1.0 + ex;
            out[token * 2 + 0] = (float)(1.0 / s);
            out[token * 2 + 1] = (float)(ex / s);
            out[NTOK * 2 + token * 2 + 0] = (float)i1;
            out[NTOK * 2 + token * 2 + 1] = (float)i2;
        }
    }
}

// ---------------------------------------------------------------------------
// fix: exact f64 recompute of flagged rows, one block (1024 thr) per row.
// x row staged in LDS; 16 lanes per expert row -> coalesced 256B W reads.
// shfl-tree reduce (deterministic) -> wave 0 f64 top-2 (validated comparator).
// ---------------------------------------------------------------------------
__global__ __launch_bounds__(1024) void moirai_fix(
        const float* __restrict__ x, const float* __restrict__ W,
        const float* __restrict__ bias,
        const int* __restrict__ count, const int* __restrict__ list,
        float* __restrict__ out) {
    __shared__ float  xsr[DD];      // 16 KB
    __shared__ double red[EE];

    const int t = threadIdx.x;
    const int e = t >> 4;           // expert 0..63
    const int j = t & 15;           // k-strip within expert
    const int n = *count;

    for (int idx = blockIdx.x; idx < n; idx += gridDim.x) {
        const int token = list[idx];
        *(float4*)&xsr[t * 4] = *(const float4*)(x + (size_t)token * DD + t * 4);
        __syncthreads();

        const float* wr = W + (size_t)e * DD;
        double a0 = 0.0, a1 = 0.0, a2 = 0.0, a3 = 0.0;
#pragma unroll 8
        for (int i = 0; i < DD / 64; i++) {
            const int k = i * 64 + j * 4;
            const float4 xv = *(const float4*)&xsr[k];
            const float4 wv = *(const float4*)(wr + k);
            a0 += (double)xv.x * (double)wv.x;
            a1 += (double)xv.y * (double)wv.y;
            a2 += (double)xv.z * (double)wv.z;
            a3 += (double)xv.w * (double)wv.w;
        }
        double s = (a0 + a1) + (a2 + a3);
#pragma unroll
        for (int off = 1; off < 16; off <<= 1)
            s += __shfl_xor(s, off);          // within 16-lane group
        if (j == 0) red[e] = s;
        __syncthreads();

        if (t < 64) {                          // wave 0: f64 top-2
            double vd = red[t] + (double)bias[t];
            double e1 = vd, e2 = -1.0e300;
            int    f1 = t,  f2 = 127;
#pragma unroll
            for (int off = 1; off < 64; off <<= 1) {
                double u1 = __shfl_xor(e1, off);
                double u2 = __shfl_xor(e2, off);
                int    j1 = __shfl_xor(f1, off);
                int    j2 = __shfl_xor(f2, off);
                bool u1_beats_e1 = (u1 > e1) || (u1 == e1 && j1 < f1);
                if (u1_beats_e1) {
                    bool e1_beats_u2 = (e1 > u2) || (e1 == u2 && f1 < j2);
                    if (e1_beats_u2) { e2 = e1; f2 = f1; }
                    else             { e2 = u2; f2 = j2; }
                    e1 = u1; f1 = j1;
                } else {
                    bool u1_beats_e2 = (u1 > e2) || (u1 == e2 && j1 < f2);
                    if (u1_beats_e2) { e2 = u1; f2 = j1; }
                }
            }
            if (t == 0) {
                double ex = exp(e2 - e1);
                double sm = 1.0 + ex;
                out[token * 2 + 0] = (float)(1.0 / sm);
                out[token * 2 + 1] = (float)(ex / sm);
                out[NTOK * 2 + token * 2 + 0] = (float)f1;
                out[NTOK * 2 + token * 2 + 1] = (float)f2;
            }
        }
        __syncthreads();   // LDS reuse guard
    }
}

// ---------------------------------------------------------------------------
extern "C" void kernel_launch(void* const* d_in, const int* in_sizes, int n_in,
                              void* d_out, int out_size, void* d_ws, size_t ws_size,
                              hipStream_t stream) {
    const float* x = (const float*)d_in[0];
    const float* W = (const float*)d_in[1];
    const float* b = (const float*)d_in[2];
    float* out = (float*)d_out;

    // ws layout: [count|list : 64 KB][Wh 512 KB][Wl 512 KB]
    const size_t HDR = 65536;
    const size_t WSZ = (size_t)EE * DD * 2;
    int*            count = (int*)d_ws;
    int*            list  = (int*)d_ws + 1;
    unsigned short* Wh    = (unsigned short*)((char*)d_ws + HDR);
    unsigned short* Wl    = (unsigned short*)((char*)d_ws + HDR + WSZ);

    moirai_prep<<<(EE * DD + 255) / 256, 256, 0, stream>>>(W, Wh, Wl, count);
    moirai_gemm<<<NTOK / BM, 512, 0, stream>>>(x, Wh, Wl, b, out, count, list);
    moirai_fix<<<256, 1024, 0, stream>>>(x, W, b, count, list, out);
}

// Round 11
// 101.048 us; speedup vs baseline: 1.1300x; 1.1300x over previous
//
#include <hip/hip_runtime.h>
#include <math.h>

#define DD 4096
#define EE 64
#define NTOK 8192
#define BM 64            // tokens per block
#define KC 32            // K-chunk (one K=32 MFMA step)
#define NMB (NTOK / BM)  // 128 m-blocks
#define TAU 4e-3f        // near-tie flag threshold (3-term err ~1e-5 RMS)

typedef __attribute__((ext_vector_type(8))) short short8;
typedef __attribute__((ext_vector_type(4))) float f32x4;

__device__ __forceinline__ unsigned short f2bf(float f) {   // RNE bf16
    unsigned int u = __float_as_uint(f);
    return (unsigned short)((u + 0x7FFFu + ((u >> 16) & 1u)) >> 16);
}
__device__ __forceinline__ float bf2f(unsigned short h) {
    return __uint_as_float((unsigned int)h << 16);
}

// ---------------------------------------------------------------------------
// prep: W -> bf16 hi/lo split (Wh, Wl); zero the flag counter.
// ---------------------------------------------------------------------------
__global__ void moirai_prep(const float* __restrict__ W,
                            unsigned short* __restrict__ Wh,
                            unsigned short* __restrict__ Wl,
                            int* __restrict__ count) {
    int i = blockIdx.x * 256 + threadIdx.x;
    if (i == 0) *count = 0;
    if (i < EE * DD) {
        float w = W[i];
        unsigned short h = f2bf(w);
        Wh[i] = h;
        Wl[i] = f2bf(w - bf2f(h));
    }
}

// ---------------------------------------------------------------------------
// gemm: 3-term split-bf16 MFMA. Block = 256 thr (4 waves) = 64 tok x 64 exp
// x K-slice. Wave wv owns m-tile wv and all 4 n-tiles (acc HH/HL/LH x4 = 48
// VGPR). x: global->reg (2-deep prefetch) -> cvt h/l -> swizzled LDS
// (fragment-contiguous slots, conflict-free b128 both sides), double-buffered,
// ONE barrier/chunk. W: per-lane global loads (L1/L2-resident, no LDS).
// Partials -> part[ks][token][e].
// ---------------------------------------------------------------------------
__global__ __launch_bounds__(256, 3) void moirai_gemm(
        const float* __restrict__ x,
        const unsigned short* __restrict__ Wh,
        const unsigned short* __restrict__ Wl,
        float* __restrict__ part, int* __restrict__ count, int kslen) {
    // 2 buffers x 256 fragment-slots x 8 bf16 (4 KB each array-buffer)
    __shared__ __align__(16) unsigned short xs_h[2][2048];
    __shared__ __align__(16) unsigned short xs_l[2][2048];

    const int t    = threadIdx.x;
    const int lane = t & 63;
    const int wv   = t >> 6;             // wave = m-tile 0..3
    const int mblk = blockIdx.x & (NMB - 1);
    const int ks   = blockIdx.x >> 7;    // grid = NMB * KS
    const int m0   = mblk * BM;
    const int k0   = ks * kslen;

    if (blockIdx.x == 0 && t == 0) *count = 0;

    const int fr = lane & 15;            // fragment row (token/expert in tile)
    const int fg = lane >> 4;            // k-group (8 elems)

    // staging: thread t handles (srow, sfg): 8 consecutive f32 of one row
    const int srow = t >> 2;             // 0..63
    const int sfg  = t & 3;
    const int wslot = ((srow >> 4) * 4 + sfg) * 16 + ((srow & 15) ^ (sfg << 1));
    const int rslot = (wv * 4 + fg) * 16 + (fr ^ (fg << 1));

    // per-lane W bases (bf16 elems); L1-resident across the block's waves
    const unsigned short* whb = Wh + (size_t)fr * DD + k0 + fg * 8;
    const unsigned short* wlb = Wl + (size_t)fr * DD + k0 + fg * 8;
    const float*          xb  = x  + (size_t)(m0 + srow) * DD + k0 + sfg * 8;

    f32x4 aHH[4], aHL[4], aLH[4];
#pragma unroll
    for (int nt = 0; nt < 4; nt++) {
        aHH[nt] = f32x4{0.f, 0.f, 0.f, 0.f};
        aHL[nt] = f32x4{0.f, 0.f, 0.f, 0.f};
        aLH[nt] = f32x4{0.f, 0.f, 0.f, 0.f};
    }

    float4 pA0, pA1, pB0, pB1;
    auto ldx = [&](int c, float4& a, float4& b) {
        a = *(const float4*)(xb + c * KC);
        b = *(const float4*)(xb + c * KC + 4);
    };
    auto stg = [&](int p, const float4& a, const float4& b) {
        const float v[8] = {a.x, a.y, a.z, a.w, b.x, b.y, b.z, b.w};
        short8 h, l;
#pragma unroll
        for (int i = 0; i < 8; i++) {
            unsigned short hh = f2bf(v[i]);
            h[i] = (short)hh;
            l[i] = (short)f2bf(v[i] - bf2f(hh));
        }
        *(short8*)&xs_h[p][wslot * 8] = h;
        *(short8*)&xs_l[p][wslot * 8] = l;
    };

    const int nch = kslen / KC;
    ldx(0, pA0, pA1);
    stg(0, pA0, pA1);
    if (nch > 1) ldx(1, pB0, pB1);
    __syncthreads();

    for (int c = 0; c < nch; c++) {
        const int p = c & 1;

        // B fragments for this chunk (global, L1/L2; overlapped with MFMA)
        short8 bh[4], bl[4];
#pragma unroll
        for (int nt = 0; nt < 4; nt++) {
            bh[nt] = *(const short8*)(whb + (size_t)nt * 16 * DD + c * KC);
            bl[nt] = *(const short8*)(wlb + (size_t)nt * 16 * DD + c * KC);
        }

        // x prefetch 2 chunks ahead into the register set freed by last stg
        if (c + 2 < nch) {
            if (p == 0) ldx(c + 2, pA0, pA1);
            else        ldx(c + 2, pB0, pB1);
        }

        // A fragments (conflict-free swizzled b128)
        const short8 ah = *(const short8*)&xs_h[p][rslot * 8];
        const short8 al = *(const short8*)&xs_l[p][rslot * 8];

#pragma unroll
        for (int nt = 0; nt < 4; nt++) {
            aHH[nt] = __builtin_amdgcn_mfma_f32_16x16x32_bf16(ah, bh[nt], aHH[nt], 0, 0, 0);
            aHL[nt] = __builtin_amdgcn_mfma_f32_16x16x32_bf16(ah, bl[nt], aHL[nt], 0, 0, 0);
            aLH[nt] = __builtin_amdgcn_mfma_f32_16x16x32_bf16(al, bh[nt], aLH[nt], 0, 0, 0);
        }

        // stage chunk c+1 into the other buffer (no read/write overlap)
        if (c + 1 < nch) {
            if (p == 0) stg(1, pB0, pB1);
            else        stg(0, pA0, pA1);
        }
        __syncthreads();   // single barrier per chunk
    }

    // C/D (verified m89/m91): col = lane&15 -> expert, row = fg*4+j -> token
#pragma unroll
    for (int nt = 0; nt < 4; nt++) {
#pragma unroll
        for (int j = 0; j < 4; j++) {
            const int token = m0 + wv * 16 + fg * 4 + j;
            const float v = (aHH[nt][j] + aHL[nt][j]) + aLH[nt][j];
            part[((size_t)ks * NTOK + token) * EE + nt * 16 + fr] = v;
        }
    }
}

// ---------------------------------------------------------------------------
// topk pass 1: wave per token, lane = expert. f32 sum of KS partials + bias
// -> top-2 + third-max. Near-tie rows appended to flagged list (fix kernel
// overwrites them). Output: [gate_probs 16384 f32][indices-as-f32 16384].
// ---------------------------------------------------------------------------
__global__ void moirai_topk(const float* __restrict__ part,
                            const float* __restrict__ bias,
                            float* __restrict__ out,
                            int* __restrict__ count, int* __restrict__ list,
                            int KS) {
    const int lane  = threadIdx.x & 63;
    const int token = blockIdx.x * 4 + (threadIdx.x >> 6);

    float v = bias[lane];
    for (int ks = 0; ks < KS; ks++)
        v += part[((size_t)ks * NTOK + token) * EE + lane];

    // f32 top-2 butterfly with jax tie-break (lower index wins ties)
    float v1 = v, v2 = -3.4e38f;
    int   i1 = lane, i2 = 127;
#pragma unroll
    for (int off = 1; off < 64; off <<= 1) {
        float u1 = __shfl_xor(v1, off);
        float u2 = __shfl_xor(v2, off);
        int   j1 = __shfl_xor(i1, off);
        int   j2 = __shfl_xor(i2, off);
        bool u1_beats_v1 = (u1 > v1) || (u1 == v1 && j1 < i1);
        if (u1_beats_v1) {
            bool v1_beats_u2 = (v1 > u2) || (v1 == u2 && i1 < j2);
            if (v1_beats_u2) { v2 = v1; i2 = i1; }
            else             { v2 = u2; i2 = j2; }
            v1 = u1; i1 = j1;
        } else {
            bool u1_beats_v2 = (u1 > v2) || (u1 == v2 && j1 < i2);
            if (u1_beats_v2) { v2 = u1; i2 = j1; }
        }
    }

    // third-largest value (exclude top-2 by index)
    float ve = (lane == i1 || lane == i2) ? -3.4e38f : v;
#pragma unroll
    for (int off = 1; off < 64; off <<= 1)
        ve = fmaxf(ve, __shfl_xor(ve, off));

    if (lane == 0) {
        if ((v1 - v2 < TAU) || (v2 - ve < TAU)) {
            int pos = atomicAdd(count, 1);
            list[pos] = token;
        }
        double ex = exp((double)v2 - (double)v1);   // v1 >= v2 -> stable
        double s  = 1.0 + ex;
        out[token * 2 + 0] = (float)(1.0 / s);
        out[token * 2 + 1] = (float)(ex / s);
        out[NTOK * 2 + token * 2 + 0] = (float)i1;
        out[NTOK * 2 + token * 2 + 1] = (float)i2;
    }
}

// ---------------------------------------------------------------------------
// fix: exact f64 recompute of flagged rows, one block (1024 thr) per row.
// x row staged in LDS; 16 lanes per expert row -> coalesced 64B W reads.
// shfl-tree reduce (deterministic) -> wave 0 f64 top-2 (validated comparator).
// ---------------------------------------------------------------------------
__global__ __launch_bounds__(1024) void moirai_fix(
        const float* __restrict__ x, const float* __restrict__ W,
        const float* __restrict__ bias,
        const int* __restrict__ count, const int* __restrict__ list,
        float* __restrict__ out) {
    __shared__ float  xsr[DD];      // 16 KB
    __shared__ double red[EE];

    const int t = threadIdx.x;
    const int e = t >> 4;           // expert 0..63
    const int j = t & 15;           // k-strip within expert
    const int n = *count;

    for (int idx = blockIdx.x; idx < n; idx += gridDim.x) {
        const int token = list[idx];
        *(float4*)&xsr[t * 4] = *(const float4*)(x + (size_t)token * DD + t * 4);
        __syncthreads();

        const float* wr = W + (size_t)e * DD;
        double a0 = 0.0, a1 = 0.0, a2 = 0.0, a3 = 0.0;
#pragma unroll 8
        for (int i = 0; i < DD / 64; i++) {
            const int k = i * 64 + j * 4;
            const float4 xv = *(const float4*)&xsr[k];
            const float4 wv = *(const float4*)(wr + k);
            a0 += (double)xv.x * (double)wv.x;
            a1 += (double)xv.y * (double)wv.y;
            a2 += (double)xv.z * (double)wv.z;
            a3 += (double)xv.w * (double)wv.w;
        }
        double s = (a0 + a1) + (a2 + a3);
#pragma unroll
        for (int off = 1; off < 16; off <<= 1)
            s += __shfl_xor(s, off);          // within 16-lane group
        if (j == 0) red[e] = s;
        __syncthreads();

        if (t < 64) {                          // wave 0: f64 top-2
            double vd = red[t] + (double)bias[t];
            double e1 = vd, e2 = -1.0e300;
            int    f1 = t,  f2 = 127;
#pragma unroll
            for (int off = 1; off < 64; off <<= 1) {
                double u1 = __shfl_xor(e1, off);
                double u2 = __shfl_xor(e2, off);
                int    j1 = __shfl_xor(f1, off);
                int    j2 = __shfl_xor(f2, off);
                bool u1_beats_e1 = (u1 > e1) || (u1 == e1 && j1 < f1);
                if (u1_beats_e1) {
                    bool e1_beats_u2 = (e1 > u2) || (e1 == u2 && f1 < j2);
                    if (e1_beats_u2) { e2 = e1; f2 = f1; }
                    else             { e2 = u2; f2 = j2; }
                    e1 = u1; f1 = j1;
                } else {
                    bool u1_beats_e2 = (u1 > e2) || (u1 == e2 && j1 < f2);
                    if (u1_beats_e2) { e2 = u1; f2 = j1; }
                }
            }
            if (t == 0) {
                double ex = exp(e2 - e1);
                double sm = 1.0 + ex;
                out[token * 2 + 0] = (float)(1.0 / sm);
                out[token * 2 + 1] = (float)(ex / sm);
                out[NTOK * 2 + token * 2 + 0] = (float)f1;
                out[NTOK * 2 + token * 2 + 1] = (float)f2;
            }
        }
        __syncthreads();   // LDS reuse guard
    }
}

// ---------------------------------------------------------------------------
extern "C" void kernel_launch(void* const* d_in, const int* in_sizes, int n_in,
                              void* d_out, int out_size, void* d_ws, size_t ws_size,
                              hipStream_t stream) {
    const float* x = (const float*)d_in[0];
    const float* W = (const float*)d_in[1];
    const float* b = (const float*)d_in[2];
    float* out = (float*)d_out;

    // ws layout: [count|list : 64 KB][Wh 512 KB][Wl 512 KB][partials]
    const size_t HDR = 65536;
    const size_t WSZ = (size_t)EE * DD * 2;
    int*            count = (int*)d_ws;
    int*            list  = (int*)d_ws + 1;
    unsigned short* Wh    = (unsigned short*)((char*)d_ws + HDR);
    unsigned short* Wl    = (unsigned short*)((char*)d_ws + HDR + WSZ);
    float*          part  = (float*)((char*)d_ws + HDR + 2 * WSZ);

    int KS = 8;  // K-split; kslen stays a multiple of KC
    while (KS > 1 && HDR + 2 * WSZ + (size_t)KS * NTOK * EE * 4 > ws_size)
        KS >>= 1;
    const int kslen = DD / KS;

    moirai_prep<<<(EE * DD + 255) / 256, 256, 0, stream>>>(W, Wh, Wl, count);
    moirai_gemm<<<NMB * KS, 256, 0, stream>>>(x, Wh, Wl, part, count, kslen);
    moirai_topk<<<NTOK / 4, 256, 0, stream>>>(part, b, out, count, list, KS);
    moirai_fix<<<256, 1024, 0, stream>>>(x, W, b, count, list, out);
}